// Round 1
// baseline (18722.977 us; speedup 1.0000x reference)
//
#include <hip/hip_runtime.h>
#include <cstdint>
#include <cstddef>

#define N_NODES 20000
#define N_EDGES 640000

// ---------------------------------------------------------------- utilities
__global__ __launch_bounds__(256) void zero_i32(int* __restrict__ p, int n) {
    int i = blockIdx.x * 256 + threadIdx.x;
    if (i < n) p[i] = 0;
}

// ---------------------------------------------------------------- CSR build
__global__ __launch_bounds__(256) void hist_kernel(const int* __restrict__ rows,
                                                   int* __restrict__ counts) {
    int e = blockIdx.x * 256 + threadIdx.x;
    if (e < N_EDGES) atomicAdd(&counts[rows[e]], 1);
}

__global__ __launch_bounds__(1024) void scan_kernel(const int* __restrict__ counts,
                                                    int* __restrict__ row_ptr) {
    __shared__ int part[1024];
    const int CH = 20;  // 1024*20 = 20480 >= 20000
    int tid = threadIdx.x;
    int t0 = tid * CH;
    int s = 0;
    for (int i = 0; i < CH; ++i) {
        int p = t0 + i;
        if (p < N_NODES) s += counts[p];
    }
    part[tid] = s;
    __syncthreads();
    for (int off = 1; off < 1024; off <<= 1) {
        int v = (tid >= off) ? part[tid - off] : 0;
        __syncthreads();
        if (tid >= off) part[tid] += v;
        __syncthreads();
    }
    int base = (tid == 0) ? 0 : part[tid - 1];
    for (int i = 0; i < CH; ++i) {
        int p = t0 + i;
        if (p < N_NODES) {
            row_ptr[p] = base;
            base += counts[p];
            if (p == N_NODES - 1) row_ptr[N_NODES] = base;
        }
    }
}

__global__ __launch_bounds__(256) void fill_kernel(const int* __restrict__ rows,
                                                   const int* __restrict__ cols,
                                                   const float* __restrict__ vals,
                                                   const int* __restrict__ row_ptr,
                                                   int* __restrict__ fillctr,
                                                   int* __restrict__ cols_s,
                                                   float* __restrict__ vals_s) {
    int e = blockIdx.x * 256 + threadIdx.x;
    if (e < N_EDGES) {
        int r = rows[e];
        int pos = atomicAdd(&fillctr[r], 1);
        int idx = row_ptr[r] + pos;
        cols_s[idx] = cols[e];
        vals_s[idx] = vals[e];
    }
}

// ---------------------------------------------------------------- GEMM
// C[M,Nc] = act(A[M,K] @ B[K,Nc] + bias). act: 0=none, 1=relu.
__global__ __launch_bounds__(256) void gemm_bias_act(
    const float* __restrict__ A, const float* __restrict__ B,
    const float* __restrict__ bias, float* __restrict__ C,
    int M, int K, int Nc, int act) {
    const int BK = 16;
    __shared__ float As[16][68];
    __shared__ float Bs[16][68];
    int tid = threadIdx.x;
    int tx = tid & 15, ty = tid >> 4;
    int row0 = blockIdx.y * 64, col0 = blockIdx.x * 64;
    float acc[4][4] = {};
    int ar = tid >> 2;          // 0..63 : A tile row
    int ak = (tid & 3) * 4;     // 0,4,8,12
    int bc = tid & 63;          // 0..63 : B tile col
    int bk = (tid >> 6) * 4;    // 0,4,8,12
    for (int k0 = 0; k0 < K; k0 += BK) {
        int grow = row0 + ar;
#pragma unroll
        for (int j = 0; j < 4; ++j) {
            int gk = k0 + ak + j;
            As[ak + j][ar] = (grow < M && gk < K) ? A[(size_t)grow * K + gk] : 0.f;
        }
        int gcol = col0 + bc;
#pragma unroll
        for (int j = 0; j < 4; ++j) {
            int gk = k0 + bk + j;
            Bs[bk + j][bc] = (gk < K && gcol < Nc) ? B[(size_t)gk * Nc + gcol] : 0.f;
        }
        __syncthreads();
#pragma unroll
        for (int kk = 0; kk < BK; ++kk) {
            float a[4], b[4];
#pragma unroll
            for (int i = 0; i < 4; ++i) a[i] = As[kk][ty * 4 + i];
#pragma unroll
            for (int i = 0; i < 4; ++i) b[i] = Bs[kk][tx * 4 + i];
#pragma unroll
            for (int i = 0; i < 4; ++i)
#pragma unroll
                for (int j = 0; j < 4; ++j) acc[i][j] += a[i] * b[j];
        }
        __syncthreads();
    }
#pragma unroll
    for (int i = 0; i < 4; ++i) {
        int grow = row0 + ty * 4 + i;
        if (grow >= M) continue;
#pragma unroll
        for (int j = 0; j < 4; ++j) {
            int gcol = col0 + tx * 4 + j;
            if (gcol >= Nc) continue;
            float v = acc[i][j];
            if (bias) v += bias[gcol];
            if (act == 1) v = v > 0.f ? v : 0.f;
            C[(size_t)grow * Nc + gcol] = v;
        }
    }
}

// ---------------------------------------------------------------- SpMM + act
// t[r,f] = f( sum_e vals_s[e] * sup[cols_s[e], f] ),  f = elu(leaky_relu(.,0.2))
__global__ __launch_bounds__(256) void spmm_act(const float* __restrict__ sup,
                                                const int* __restrict__ row_ptr,
                                                const int* __restrict__ cols_s,
                                                const float* __restrict__ vals_s,
                                                float* __restrict__ t, int C) {
    int r = blockIdx.x;
    int f = blockIdx.y * 256 + threadIdx.x;
    int s = row_ptr[r], e = row_ptr[r + 1];
    float acc = 0.f;
    for (int i = s; i < e; ++i) {
        float v = vals_s[i];
        int c = cols_s[i];
        if (f < C) acc += v * sup[(size_t)c * C + f];
    }
    if (f < C) {
        float a = acc;
        // a>0: leaky & elu pass through; a<=0: elu(0.2a) = exp(0.2a)-1
        t[(size_t)r * C + f] = a > 0.f ? a : (expf(0.2f * a) - 1.0f);
    }
}

// ---------------------------------------------------------------- BatchNorm
__global__ __launch_bounds__(256) void col_stats(const float* __restrict__ t,
                                                 float* __restrict__ sum,
                                                 float* __restrict__ sumsq, int C) {
    int c = blockIdx.x * 256 + threadIdx.x;
    int r0 = blockIdx.y * 500;
    if (c >= C) return;
    float s = 0.f, ss = 0.f;
    for (int r = r0; r < r0 + 500; ++r) {
        float v = t[(size_t)r * C + c];
        s += v;
        ss += v * v;
    }
    atomicAdd(&sum[c], s);
    atomicAdd(&sumsq[c], ss);
}

__global__ __launch_bounds__(256) void bn_apply(const float* __restrict__ t,
                                                const float* __restrict__ sum,
                                                const float* __restrict__ sumsq,
                                                float* __restrict__ h, int C) {
    int c = blockIdx.x * 256 + threadIdx.x;
    int r = blockIdx.y;
    if (c >= C) return;
    float mean = sum[c] * (1.0f / N_NODES);
    float var = sumsq[c] * (1.0f / N_NODES) - mean * mean;
    float rs = rsqrtf(var + 1e-5f);
    h[(size_t)r * C + c] = (t[(size_t)r * C + c] - mean) * rs;
}

// ---------------------------------------------------------------- attention head
// u = normalize(softmax(tanh(coms @ W + b)))   coms = [h1|h2|h3|h4] per row
__global__ __launch_bounds__(256) void mlp_u(const float* __restrict__ h1,
                                             const float* __restrict__ h2,
                                             const float* __restrict__ h3,
                                             const float* __restrict__ h4,
                                             const float* __restrict__ W,
                                             const float* __restrict__ b,
                                             float* __restrict__ u) {
    int lane = threadIdx.x & 63;
    int wv = threadIdx.x >> 6;
    int row = blockIdx.x * 4 + wv;
    if (row >= N_NODES) return;
    float acc[5] = {0.f, 0.f, 0.f, 0.f, 0.f};
    const float* hs[4] = {h1, h2, h3, h4};
    const int Cs[4] = {500, 500, 2000, 10};
    const int Woff[4] = {0, 500, 1000, 3000};
    for (int sg = 0; sg < 4; ++sg) {
        const float* hp = hs[sg] + (size_t)row * Cs[sg];
        const float* wp = W + (size_t)Woff[sg] * 5;
        for (int k = lane; k < Cs[sg]; k += 64) {
            float a = hp[k];
#pragma unroll
            for (int j = 0; j < 5; ++j) acc[j] += a * wp[k * 5 + j];
        }
    }
#pragma unroll
    for (int j = 0; j < 5; ++j)
        for (int off = 32; off > 0; off >>= 1) acc[j] += __shfl_down(acc[j], off, 64);
    if (lane == 0) {
        float t[5], m = -1e30f;
#pragma unroll
        for (int j = 0; j < 5; ++j) {
            t[j] = tanhf(acc[j] + b[j]);
            m = fmaxf(m, t[j]);
        }
        float s = 0.f;
#pragma unroll
        for (int j = 0; j < 5; ++j) {
            t[j] = expf(t[j] - m);
            s += t[j];
        }
        float inv = 1.0f / s;
        float n2 = 0.f;
#pragma unroll
        for (int j = 0; j < 5; ++j) {
            t[j] *= inv;
            n2 += t[j] * t[j];
        }
        float nrm = fmaxf(sqrtf(n2), 1e-12f);
        float innrm = 1.0f / nrm;
#pragma unroll
        for (int j = 0; j < 5; ++j) u[(size_t)row * 5 + j] = t[j] * innrm;
    }
}

__global__ __launch_bounds__(256) void zout_kernel(const float* __restrict__ h1,
                                                   const float* __restrict__ h2,
                                                   const float* __restrict__ h3,
                                                   const float* __restrict__ h4,
                                                   const float* __restrict__ u,
                                                   float* __restrict__ out) {
    int c = blockIdx.x * 256 + threadIdx.x;
    int row = blockIdx.y;
    if (c >= 3010) return;
    int seg, cl;
    const float* hp;
    if (c < 500)       { seg = 0; cl = c;        hp = h1 + (size_t)row * 500; }
    else if (c < 1000) { seg = 1; cl = c - 500;  hp = h2 + (size_t)row * 500; }
    else if (c < 3000) { seg = 2; cl = c - 1000; hp = h3 + (size_t)row * 2000; }
    else               { seg = 3; cl = c - 3000; hp = h4 + (size_t)row * 10; }
    out[(size_t)row * 3010 + c] = u[(size_t)row * 5 + seg] * hp[cl];
}

// ---------------------------------------------------------------- launch
extern "C" void kernel_launch(void* const* d_in, const int* in_sizes, int n_in,
                              void* d_out, int out_size, void* d_ws, size_t ws_size,
                              hipStream_t stream) {
    const float* x = (const float*)d_in[0];
    const int* adj_rows  = (const int*)d_in[1];
    const int* adj_cols  = (const int*)d_in[2];
    const float* adj_vals = (const float*)d_in[3];
    const int* fadj_rows = (const int*)d_in[4];
    const int* fadj_cols = (const int*)d_in[5];
    const float* fadj_vals = (const float*)d_in[6];
    const int* f1_rows = (const int*)d_in[7];
    const int* f1_cols = (const int*)d_in[8];
    const float* f1_vals = (const float*)d_in[9];
    const int* f2_rows = (const int*)d_in[10];
    const int* f2_cols = (const int*)d_in[11];
    const float* f2_vals = (const float*)d_in[12];
    const float* feaW[4]  = {(const float*)d_in[13], (const float*)d_in[14],
                             (const float*)d_in[15], (const float*)d_in[16]};
    const float* topoW[4] = {(const float*)d_in[17], (const float*)d_in[18],
                             (const float*)d_in[19], (const float*)d_in[20]};
    const float* We1 = (const float*)d_in[21]; const float* be1 = (const float*)d_in[22];
    const float* We2 = (const float*)d_in[23]; const float* be2 = (const float*)d_in[24];
    const float* We3 = (const float*)d_in[25]; const float* be3 = (const float*)d_in[26];
    const float* Wz1 = (const float*)d_in[27]; const float* bz1 = (const float*)d_in[28];
    const float* Wz2 = (const float*)d_in[29]; const float* bz2 = (const float*)d_in[30];
    const float* Wd0 = (const float*)d_in[31]; const float* bd0 = (const float*)d_in[32];
    const float* Wd1 = (const float*)d_in[33]; const float* bd1 = (const float*)d_in[34];
    const float* Wd2 = (const float*)d_in[35]; const float* bd2 = (const float*)d_in[36];
    const float* Wd3 = (const float*)d_in[37]; const float* bd3 = (const float*)d_in[38];
    const float* Wxb = (const float*)d_in[39]; const float* bxb = (const float*)d_in[40];
    const float* mlpW = (const float*)d_in[41]; const float* mlpb = (const float*)d_in[42];

    float* out = (float*)d_out;
    float* out_xbar = out;                    // [20000,1000]
    float* out_z = out + 20000000;            // [20000,10]
    float* out_fea4 = out + 20200000;         // [20000,10]
    float* out_topo4 = out + 20400000;
    float* out_feadiff4 = out + 20600000;
    float* out_topodiff4 = out + 20800000;
    float* out_zout = out + 21000000;         // [20000,3010]

    char* w = (char*)d_ws;
    auto alloc = [&](size_t bytes) -> char* {
        char* p = w;
        w += (bytes + 255) & ~(size_t)255;
        return p;
    };
    float* bufB  = (float*)alloc((size_t)N_NODES * 2000 * 4);  // sup
    float* bufC  = (float*)alloc((size_t)N_NODES * 2000 * 4);  // agg/t/h (in-place BN)
    float* feah1 = (float*)alloc((size_t)N_NODES * 500 * 4);
    float* feah2 = (float*)alloc((size_t)N_NODES * 500 * 4);
    float* feah3 = (float*)alloc((size_t)N_NODES * 2000 * 4);
    float* z1buf = (float*)alloc((size_t)N_NODES * 10 * 4);
    float* dsmall = (float*)alloc((size_t)N_NODES * 10 * 4);
    float* ubuf  = (float*)alloc((size_t)N_NODES * 5 * 4);
    float* ssum  = (float*)alloc(2000 * 4);
    float* ssq   = (float*)alloc(2000 * 4);
    int* counts  = (int*)alloc(N_NODES * 4);
    int* fillctr = (int*)alloc(N_NODES * 4);
    int* row_ptr = (int*)alloc((N_NODES + 1) * 4);
    int* cols_s  = (int*)alloc((size_t)N_EDGES * 4);
    float* vals_s = (float*)alloc((size_t)N_EDGES * 4);

    auto gemm = [&](const float* A, const float* B, const float* bias, float* Cc,
                    int M, int K, int Nc, int act) {
        dim3 g((Nc + 63) / 64, (M + 63) / 64);
        gemm_bias_act<<<g, 256, 0, stream>>>(A, B, bias, Cc, M, K, Nc, act);
    };

    // ---------------- AE branch ----------------
    gemm(x, We1, be1, feah1, N_NODES, 1000, 500, 1);     // h1
    gemm(feah1, We2, be2, feah2, N_NODES, 500, 500, 1);  // h2
    gemm(feah2, We3, be3, bufC, N_NODES, 500, 2000, 1);  // h3
    gemm(bufC, Wz1, bz1, z1buf, N_NODES, 2000, 10, 0);   // z1
    gemm(z1buf, Wz2, bz2, out_z, N_NODES, 10, 10, 0);    // z   -> output 1
    gemm(out_z, Wd0, bd0, dsmall, N_NODES, 10, 10, 1);   // d0
    gemm(dsmall, Wd1, bd1, bufC, N_NODES, 10, 2000, 1);  // d1
    gemm(bufC, Wd2, bd2, bufB, N_NODES, 2000, 500, 1);   // d2
    gemm(bufB, Wd3, bd3, feah1, N_NODES, 500, 500, 1);   // d3 (feah1 as scratch)
    gemm(feah1, Wxb, bxb, out_xbar, N_NODES, 500, 1000, 0);  // x_bar -> output 0

    // ---------------- GNN branches ----------------
    struct Br {
        const int* rows; const int* cols; const float* vals;
        const float* const* W;
        float* dest[4];
    };
    Br brs[4] = {
        {fadj_rows, fadj_cols, fadj_vals, feaW, {feah1, feah2, feah3, out_fea4}},   // fea_hs
        {adj_rows, adj_cols, adj_vals, topoW, {bufC, bufC, bufC, out_topo4}},       // topo_hs
        {f2_rows, f2_cols, f2_vals, feaW, {bufC, bufC, bufC, out_feadiff4}},        // fea_diff
        {f1_rows, f1_cols, f1_vals, topoW, {bufC, bufC, bufC, out_topodiff4}},      // topo_diff
    };
    const int inD[4] = {1000, 500, 500, 2000};
    const int outD[4] = {500, 500, 2000, 10};

    for (int b = 0; b < 4; ++b) {
        // CSR build for this adjacency
        zero_i32<<<(N_NODES + 255) / 256, 256, 0, stream>>>(counts, N_NODES);
        hist_kernel<<<(N_EDGES + 255) / 256, 256, 0, stream>>>(brs[b].rows, counts);
        scan_kernel<<<1, 1024, 0, stream>>>(counts, row_ptr);
        zero_i32<<<(N_NODES + 255) / 256, 256, 0, stream>>>(fillctr, N_NODES);
        fill_kernel<<<(N_EDGES + 255) / 256, 256, 0, stream>>>(
            brs[b].rows, brs[b].cols, brs[b].vals, row_ptr, fillctr, cols_s, vals_s);

        const float* h = x;
        for (int L = 0; L < 4; ++L) {
            int C = outD[L];
            gemm(h, brs[b].W[L], nullptr, bufB, N_NODES, inD[L], C, 0);  // sup
            spmm_act<<<dim3(N_NODES, (C + 255) / 256), 256, 0, stream>>>(
                bufB, row_ptr, cols_s, vals_s, bufC, C);                 // t = f(agg)
            zero_i32<<<(2 * C + 255) / 256, 256, 0, stream>>>((int*)ssum, C);
            zero_i32<<<(2 * C + 255) / 256, 256, 0, stream>>>((int*)ssq, C);
            col_stats<<<dim3((C + 255) / 256, 40), 256, 0, stream>>>(bufC, ssum, ssq, C);
            bn_apply<<<dim3((C + 255) / 256, N_NODES), 256, 0, stream>>>(
                bufC, ssum, ssq, brs[b].dest[L], C);
            h = brs[b].dest[L];
        }
    }

    // ---------------- attention fusion head ----------------
    mlp_u<<<(N_NODES + 3) / 4, 256, 0, stream>>>(feah1, feah2, feah3, out_fea4,
                                                 mlpW, mlpb, ubuf);
    zout_kernel<<<dim3(12, N_NODES), 256, 0, stream>>>(feah1, feah2, feah3, out_fea4,
                                                       ubuf, out_zout);
}

// Round 3
// 10806.345 us; speedup vs baseline: 1.7326x; 1.7326x over previous
//
#include <hip/hip_runtime.h>
#include <cstdint>
#include <cstddef>

#define N_NODES 20000
#define N_EDGES 640000

typedef short short8 __attribute__((ext_vector_type(8)));
typedef float floatx4 __attribute__((ext_vector_type(4)));

__device__ __forceinline__ ushort f2bf(float f) {
    uint32_t u = __float_as_uint(f);
    uint32_t r = (u + 0x7fff + ((u >> 16) & 1)) >> 16;
    return (ushort)r;
}
__device__ __forceinline__ float bf2f(ushort u) {
    return __uint_as_float(((uint32_t)u) << 16);
}

// ---------------------------------------------------------------- utilities
__global__ __launch_bounds__(256) void zero_i32(int* __restrict__ p, int n) {
    int i = blockIdx.x * 256 + threadIdx.x;
    if (i < n) p[i] = 0;
}

// weight pre-transpose + bf16 convert: W[K][Nc] fp32 -> Bt[Nc][Kp] bf16 (zero pad)
__global__ __launch_bounds__(256) void transpose_w(const float* __restrict__ W,
                                                   ushort* __restrict__ Bt,
                                                   int K, int Nc, int Kp) {
    int idx = blockIdx.x * 256 + threadIdx.x;
    if (idx >= Nc * Kp) return;
    int n = idx / Kp, k = idx % Kp;
    Bt[idx] = (k < K) ? f2bf(W[(size_t)k * Nc + n]) : (ushort)0;
}

// ---------------------------------------------------------------- CSR build
__global__ __launch_bounds__(256) void hist_kernel(const int* __restrict__ rows,
                                                   int* __restrict__ counts) {
    int e = blockIdx.x * 256 + threadIdx.x;
    if (e < N_EDGES) atomicAdd(&counts[rows[e]], 1);
}

__global__ __launch_bounds__(1024) void scan_kernel(const int* __restrict__ counts,
                                                    int* __restrict__ row_ptr) {
    __shared__ int part[1024];
    const int CH = 20;
    int tid = threadIdx.x;
    int t0 = tid * CH;
    int s = 0;
    for (int i = 0; i < CH; ++i) {
        int p = t0 + i;
        if (p < N_NODES) s += counts[p];
    }
    part[tid] = s;
    __syncthreads();
    for (int off = 1; off < 1024; off <<= 1) {
        int v = (tid >= off) ? part[tid - off] : 0;
        __syncthreads();
        if (tid >= off) part[tid] += v;
        __syncthreads();
    }
    int base = (tid == 0) ? 0 : part[tid - 1];
    for (int i = 0; i < CH; ++i) {
        int p = t0 + i;
        if (p < N_NODES) {
            row_ptr[p] = base;
            base += counts[p];
            if (p == N_NODES - 1) row_ptr[N_NODES] = base;
        }
    }
}

__global__ __launch_bounds__(256) void fill_kernel(const int* __restrict__ rows,
                                                   const int* __restrict__ cols,
                                                   const float* __restrict__ vals,
                                                   const int* __restrict__ row_ptr,
                                                   int* __restrict__ fillctr,
                                                   int* __restrict__ cols_s,
                                                   float* __restrict__ vals_s) {
    int e = blockIdx.x * 256 + threadIdx.x;
    if (e < N_EDGES) {
        int r = rows[e];
        int pos = atomicAdd(&fillctr[r], 1);
        int idx = row_ptr[r] + pos;
        cols_s[idx] = cols[e];
        vals_s[idx] = vals[e];
    }
}

// ---------------------------------------------------------------- MFMA GEMM
// C[M,Nc] = act(A[M,K] @ B[K,Nc] + bias), A fp32, B pre-transposed bf16 [Nc][Kp].
// Output: Cb!=null -> bf16 else fp32. act: 1=relu.
// split=1: A staged as bf16 hi+lo, two MFMAs -> A at ~fp32 accuracy (fea branch).
// Block 256 thr = 4 waves (2x2), tile 128x128, K-step 32, mfma_f32_16x16x32_bf16.
// A frag: lane holds A[m=lane&15][k=quad*8+j]; C/D: col=lane&15,row=quad*4+reg (m89/m91).
__global__ __launch_bounds__(256) void mfma_gemm(
    const float* __restrict__ A, const ushort* __restrict__ Bt,
    const float* __restrict__ bias, float* __restrict__ Cf,
    ushort* __restrict__ Cb, int M, int K, int Nc, int Kp, int act, int split) {
    __shared__ __align__(16) ushort As[128][40];  // +8 pad breaks bank aliasing
    __shared__ __align__(16) ushort Al[128][40];  // lo part (split mode)
    __shared__ __align__(16) ushort Bs[128][40];

    int tid = threadIdx.x;
    int wave = tid >> 6, lane = tid & 63;
    int wr = (wave >> 1) * 64, wc = (wave & 1) * 64;
    int m16 = lane & 15, quad = lane >> 4;
    int row0 = blockIdx.y * 128, col0 = blockIdx.x * 128;

    floatx4 acc[4][4] = {};
    int KT = (K + 31) >> 5;
    bool k4 = (K & 3) == 0;

    for (int kt = 0; kt < KT; ++kt) {
        int k0 = kt << 5;
        // --- stage A (fp32 -> bf16 hi [+ lo]) ---
        {
            int r = tid >> 3;
            int kq = (tid & 7) << 2;
#pragma unroll
            for (int p = 0; p < 4; ++p) {
                int rr = r + p * 32;
                int grow = row0 + rr;
                float v[4] = {0.f, 0.f, 0.f, 0.f};
                int gk = k0 + kq;
                if (grow < M) {
                    const float* ap = A + (size_t)grow * K;
                    if (k4 && gk + 3 < K) {
                        float4 f = *(const float4*)(ap + gk);
                        v[0] = f.x; v[1] = f.y; v[2] = f.z; v[3] = f.w;
                    } else {
                        if (gk < K) v[0] = ap[gk];
                        if (gk + 1 < K) v[1] = ap[gk + 1];
                        if (gk + 2 < K) v[2] = ap[gk + 2];
                        if (gk + 3 < K) v[3] = ap[gk + 3];
                    }
                }
                ushort4 hi;
                hi.x = f2bf(v[0]); hi.y = f2bf(v[1]);
                hi.z = f2bf(v[2]); hi.w = f2bf(v[3]);
                *(ushort4*)&As[rr][kq] = hi;
                if (split) {
                    ushort4 lo;
                    lo.x = f2bf(v[0] - bf2f(hi.x));
                    lo.y = f2bf(v[1] - bf2f(hi.y));
                    lo.z = f2bf(v[2] - bf2f(hi.z));
                    lo.w = f2bf(v[3] - bf2f(hi.w));
                    *(ushort4*)&Al[rr][kq] = lo;
                }
            }
        }
        // --- stage B (already bf16, [Nc][Kp], Kp%32==0 so 16B aligned) ---
        {
            int n = tid >> 2;
            int ch = (tid & 3) << 3;
#pragma unroll
            for (int p = 0; p < 2; ++p) {
                int nn = n + p * 64;
                int gcol = col0 + nn;
                if (gcol < Nc) {
                    *(uint4*)&Bs[nn][ch] =
                        *(const uint4*)&Bt[(size_t)gcol * Kp + k0 + ch];
                } else {
                    uint4 z = {0, 0, 0, 0};
                    *(uint4*)&Bs[nn][ch] = z;
                }
            }
        }
        __syncthreads();
        // --- MFMA ---
        short8 a[4], b[4];
        int ko = quad * 8;
#pragma unroll
        for (int i = 0; i < 4; ++i) a[i] = *(short8*)&As[wr + i * 16 + m16][ko];
#pragma unroll
        for (int j = 0; j < 4; ++j) b[j] = *(short8*)&Bs[wc + j * 16 + m16][ko];
        if (split) {
            short8 al[4];
#pragma unroll
            for (int i = 0; i < 4; ++i) al[i] = *(short8*)&Al[wr + i * 16 + m16][ko];
#pragma unroll
            for (int i = 0; i < 4; ++i)
#pragma unroll
                for (int j = 0; j < 4; ++j)
                    acc[i][j] = __builtin_amdgcn_mfma_f32_16x16x32_bf16(
                        al[i], b[j], acc[i][j], 0, 0, 0);
        }
#pragma unroll
        for (int i = 0; i < 4; ++i)
#pragma unroll
            for (int j = 0; j < 4; ++j)
                acc[i][j] = __builtin_amdgcn_mfma_f32_16x16x32_bf16(
                    a[i], b[j], acc[i][j], 0, 0, 0);
        __syncthreads();
    }

    // --- epilogue ---
#pragma unroll
    for (int i = 0; i < 4; ++i) {
        int rbase = row0 + wr + i * 16 + quad * 4;
#pragma unroll
        for (int j = 0; j < 4; ++j) {
            int gcol = col0 + wc + j * 16 + m16;
            if (gcol >= Nc) continue;
            float bv = bias ? bias[gcol] : 0.f;
#pragma unroll
            for (int r = 0; r < 4; ++r) {
                int grow = rbase + r;
                if (grow >= M) continue;
                float v = acc[i][j][r] + bv;
                if (act) v = v > 0.f ? v : 0.f;
                if (Cb) Cb[(size_t)grow * Nc + gcol] = f2bf(v);
                else Cf[(size_t)grow * Nc + gcol] = v;
            }
        }
    }
}

// ---------------------------------------------------------------- small vector GEMM
// kept only for the 10x10 matmuls (z, d0)
__global__ __launch_bounds__(256) void gemm_small(
    const float* __restrict__ A, const float* __restrict__ B,
    const float* __restrict__ bias, float* __restrict__ C,
    int M, int K, int Nc, int act) {
    int row = blockIdx.x * 8 + (threadIdx.x >> 5);
    int c = threadIdx.x & 31;
    if (row >= M || c >= Nc) return;
    float acc = bias ? bias[c] : 0.f;
    for (int k = 0; k < K; ++k) acc += A[(size_t)row * K + k] * B[(size_t)k * Nc + c];
    if (act) acc = acc > 0.f ? acc : 0.f;
    C[(size_t)row * Nc + c] = acc;
}

// ---------------------------------------------------------------- SpMM + act (bf16)
// t[r,f] = elu(leaky(sum vals*sup[col,f])); sup/t bf16, 2 features per thread.
__global__ __launch_bounds__(256) void spmm_act_bf(const ushort* __restrict__ sup,
                                                   const int* __restrict__ row_ptr,
                                                   const int* __restrict__ cols_s,
                                                   const float* __restrict__ vals_s,
                                                   ushort* __restrict__ t, int C) {
    int r = blockIdx.x;
    int f0 = blockIdx.y * 512 + threadIdx.x * 2;
    int s = row_ptr[r], e = row_ptr[r + 1];
    float a0 = 0.f, a1 = 0.f;
    if (f0 < C) {
        for (int i = s; i < e; ++i) {
            float v = vals_s[i];
            int c = cols_s[i];
            uint u = *(const uint*)&sup[(size_t)c * C + f0];
            a0 += v * bf2f((ushort)(u & 0xffff));
            a1 += v * bf2f((ushort)(u >> 16));
        }
        float r0 = a0 > 0.f ? a0 : (expf(0.2f * a0) - 1.f);
        float r1 = a1 > 0.f ? a1 : (expf(0.2f * a1) - 1.f);
        ushort2 w;
        w.x = f2bf(r0);
        w.y = f2bf(r1);
        *(ushort2*)&t[(size_t)r * C + f0] = w;
    }
}

// ---------------------------------------------------------------- SpMM + act (fp32, fea branch)
__global__ __launch_bounds__(256) void spmm_act_f(const float* __restrict__ sup,
                                                  const int* __restrict__ row_ptr,
                                                  const int* __restrict__ cols_s,
                                                  const float* __restrict__ vals_s,
                                                  float* __restrict__ t, int C) {
    int r = blockIdx.x;
    int f = blockIdx.y * 256 + threadIdx.x;
    int s = row_ptr[r], e = row_ptr[r + 1];
    float acc = 0.f;
    for (int i = s; i < e; ++i) {
        float v = vals_s[i];
        int c = cols_s[i];
        if (f < C) acc += v * sup[(size_t)c * C + f];
    }
    if (f < C) {
        float a = acc;
        t[(size_t)r * C + f] = a > 0.f ? a : (expf(0.2f * a) - 1.0f);
    }
}

// ---------------------------------------------------------------- BatchNorm (bf16 t)
__global__ __launch_bounds__(256) void col_stats(const ushort* __restrict__ t,
                                                 float* __restrict__ sum,
                                                 float* __restrict__ sumsq, int C) {
    int c = blockIdx.x * 256 + threadIdx.x;
    int r0 = blockIdx.y * 500;
    if (c >= C) return;
    float s = 0.f, ss = 0.f;
    for (int r = r0; r < r0 + 500; ++r) {
        float v = bf2f(t[(size_t)r * C + c]);
        s += v;
        ss += v * v;
    }
    atomicAdd(&sum[c], s);
    atomicAdd(&sumsq[c], ss);
}

__global__ __launch_bounds__(256) void bn_apply(const ushort* __restrict__ t,
                                                const float* __restrict__ sum,
                                                const float* __restrict__ sumsq,
                                                float* __restrict__ h, int C) {
    int c = blockIdx.x * 256 + threadIdx.x;
    int r = blockIdx.y;
    if (c >= C) return;
    float mean = sum[c] * (1.0f / N_NODES);
    float var = sumsq[c] * (1.0f / N_NODES) - mean * mean;
    float rs = rsqrtf(var + 1e-5f);
    h[(size_t)r * C + c] = (bf2f(t[(size_t)r * C + c]) - mean) * rs;
}

// ---------------------------------------------------------------- BatchNorm (fp32 t, in-place capable)
__global__ __launch_bounds__(256) void col_stats_f(const float* __restrict__ t,
                                                   float* __restrict__ sum,
                                                   float* __restrict__ sumsq, int C) {
    int c = blockIdx.x * 256 + threadIdx.x;
    int r0 = blockIdx.y * 500;
    if (c >= C) return;
    float s = 0.f, ss = 0.f;
    for (int r = r0; r < r0 + 500; ++r) {
        float v = t[(size_t)r * C + c];
        s += v;
        ss += v * v;
    }
    atomicAdd(&sum[c], s);
    atomicAdd(&sumsq[c], ss);
}

__global__ __launch_bounds__(256) void bn_apply_f(const float* __restrict__ t,
                                                  const float* __restrict__ sum,
                                                  const float* __restrict__ sumsq,
                                                  float* __restrict__ h, int C) {
    int c = blockIdx.x * 256 + threadIdx.x;
    int r = blockIdx.y;
    if (c >= C) return;
    float mean = sum[c] * (1.0f / N_NODES);
    float var = sumsq[c] * (1.0f / N_NODES) - mean * mean;
    float rs = rsqrtf(var + 1e-5f);
    h[(size_t)r * C + c] = (t[(size_t)r * C + c] - mean) * rs;
}

// ---------------------------------------------------------------- attention head
__global__ __launch_bounds__(256) void mlp_u(const float* __restrict__ h1,
                                             const float* __restrict__ h2,
                                             const float* __restrict__ h3,
                                             const float* __restrict__ h4,
                                             const float* __restrict__ W,
                                             const float* __restrict__ b,
                                             float* __restrict__ u) {
    int lane = threadIdx.x & 63;
    int wv = threadIdx.x >> 6;
    int row = blockIdx.x * 4 + wv;
    if (row >= N_NODES) return;
    float acc[5] = {0.f, 0.f, 0.f, 0.f, 0.f};
    const float* hs[4] = {h1, h2, h3, h4};
    const int Cs[4] = {500, 500, 2000, 10};
    const int Woff[4] = {0, 500, 1000, 3000};
    for (int sg = 0; sg < 4; ++sg) {
        const float* hp = hs[sg] + (size_t)row * Cs[sg];
        const float* wp = W + (size_t)Woff[sg] * 5;
        for (int k = lane; k < Cs[sg]; k += 64) {
            float a = hp[k];
#pragma unroll
            for (int j = 0; j < 5; ++j) acc[j] += a * wp[k * 5 + j];
        }
    }
#pragma unroll
    for (int j = 0; j < 5; ++j)
        for (int off = 32; off > 0; off >>= 1) acc[j] += __shfl_down(acc[j], off, 64);
    if (lane == 0) {
        float t[5], m = -1e30f;
#pragma unroll
        for (int j = 0; j < 5; ++j) {
            t[j] = tanhf(acc[j] + b[j]);
            m = fmaxf(m, t[j]);
        }
        float s = 0.f;
#pragma unroll
        for (int j = 0; j < 5; ++j) {
            t[j] = expf(t[j] - m);
            s += t[j];
        }
        float inv = 1.0f / s;
        float n2 = 0.f;
#pragma unroll
        for (int j = 0; j < 5; ++j) {
            t[j] *= inv;
            n2 += t[j] * t[j];
        }
        float nrm = fmaxf(sqrtf(n2), 1e-12f);
        float innrm = 1.0f / nrm;
#pragma unroll
        for (int j = 0; j < 5; ++j) u[(size_t)row * 5 + j] = t[j] * innrm;
    }
}

__global__ __launch_bounds__(256) void zout_kernel(const float* __restrict__ h1,
                                                   const float* __restrict__ h2,
                                                   const float* __restrict__ h3,
                                                   const float* __restrict__ h4,
                                                   const float* __restrict__ u,
                                                   float* __restrict__ out) {
    int c = blockIdx.x * 256 + threadIdx.x;
    int row = blockIdx.y;
    if (c >= 3010) return;
    int seg, cl;
    const float* hp;
    if (c < 500)       { seg = 0; cl = c;        hp = h1 + (size_t)row * 500; }
    else if (c < 1000) { seg = 1; cl = c - 500;  hp = h2 + (size_t)row * 500; }
    else if (c < 3000) { seg = 2; cl = c - 1000; hp = h3 + (size_t)row * 2000; }
    else               { seg = 3; cl = c - 3000; hp = h4 + (size_t)row * 10; }
    out[(size_t)row * 3010 + c] = u[(size_t)row * 5 + seg] * hp[cl];
}

// ---------------------------------------------------------------- launch
extern "C" void kernel_launch(void* const* d_in, const int* in_sizes, int n_in,
                              void* d_out, int out_size, void* d_ws, size_t ws_size,
                              hipStream_t stream) {
    const float* x = (const float*)d_in[0];
    const int* adj_rows  = (const int*)d_in[1];
    const int* adj_cols  = (const int*)d_in[2];
    const float* adj_vals = (const float*)d_in[3];
    const int* fadj_rows = (const int*)d_in[4];
    const int* fadj_cols = (const int*)d_in[5];
    const float* fadj_vals = (const float*)d_in[6];
    const int* f1_rows = (const int*)d_in[7];
    const int* f1_cols = (const int*)d_in[8];
    const float* f1_vals = (const float*)d_in[9];
    const int* f2_rows = (const int*)d_in[10];
    const int* f2_cols = (const int*)d_in[11];
    const float* f2_vals = (const float*)d_in[12];
    const float* feaW[4]  = {(const float*)d_in[13], (const float*)d_in[14],
                             (const float*)d_in[15], (const float*)d_in[16]};
    const float* topoW[4] = {(const float*)d_in[17], (const float*)d_in[18],
                             (const float*)d_in[19], (const float*)d_in[20]};
    const float* We1 = (const float*)d_in[21]; const float* be1 = (const float*)d_in[22];
    const float* We2 = (const float*)d_in[23]; const float* be2 = (const float*)d_in[24];
    const float* We3 = (const float*)d_in[25]; const float* be3 = (const float*)d_in[26];
    const float* Wz1 = (const float*)d_in[27]; const float* bz1 = (const float*)d_in[28];
    const float* Wz2 = (const float*)d_in[29]; const float* bz2 = (const float*)d_in[30];
    const float* Wd0 = (const float*)d_in[31]; const float* bd0 = (const float*)d_in[32];
    const float* Wd1 = (const float*)d_in[33]; const float* bd1 = (const float*)d_in[34];
    const float* Wd2 = (const float*)d_in[35]; const float* bd2 = (const float*)d_in[36];
    const float* Wd3 = (const float*)d_in[37]; const float* bd3 = (const float*)d_in[38];
    const float* Wxb = (const float*)d_in[39]; const float* bxb = (const float*)d_in[40];
    const float* mlpW = (const float*)d_in[41]; const float* mlpb = (const float*)d_in[42];

    float* out = (float*)d_out;
    float* out_xbar = out;                    // [20000,1000]
    float* out_z = out + 20000000;            // [20000,10]
    float* out_fea4 = out + 20200000;
    float* out_topo4 = out + 20400000;
    float* out_feadiff4 = out + 20600000;
    float* out_topodiff4 = out + 20800000;
    float* out_zout = out + 21000000;         // [20000,3010]

    char* w = (char*)d_ws;
    auto alloc = [&](size_t bytes) -> char* {
        char* p = w;
        w += (bytes + 255) & ~(size_t)255;
        return p;
    };
    ushort* bufB = (ushort*)alloc((size_t)N_NODES * 2000 * 2);  // sup (bf16, br 1-3)
    ushort* bufC = (ushort*)alloc((size_t)N_NODES * 2000 * 2);  // t   (bf16, br 1-3)
    float* feah1 = (float*)alloc((size_t)N_NODES * 500 * 4);
    float* feah2 = (float*)alloc((size_t)N_NODES * 500 * 4);
    float* feah3 = (float*)alloc((size_t)N_NODES * 2000 * 4);   // aliased as AE bufF
    float* bufF  = feah3;  // AE h3 / d1 scratch; consumed before fea branch writes feah3
    float* bufH  = (float*)alloc((size_t)N_NODES * 2000 * 4);   // fea sup (fp32) / br 1-3 h scratch
    float* z1buf = (float*)alloc((size_t)N_NODES * 10 * 4);
    float* dsmall = (float*)alloc((size_t)N_NODES * 10 * 4);
    float* ubuf  = (float*)alloc((size_t)N_NODES * 5 * 4);
    float* ssum  = (float*)alloc(2000 * 4);
    float* ssq   = (float*)alloc(2000 * 4);
    int* counts  = (int*)alloc(N_NODES * 4);
    int* fillctr = (int*)alloc(N_NODES * 4);
    int* row_ptr = (int*)alloc((N_NODES + 1) * 4);
    int* cols_s  = (int*)alloc((size_t)N_EDGES * 4);
    float* vals_s = (float*)alloc((size_t)N_EDGES * 4);

    // bf16-transposed weights
    auto kpad = [](int K) { return ((K + 31) / 32) * 32; };
    struct TW { const float* W; int K, Nc, Kp; ushort* Bt; };
    TW tw[16] = {
        {We1, 1000, 500, 1024, nullptr}, {We2, 500, 500, 512, nullptr},
        {We3, 500, 2000, 512, nullptr},  {Wz1, 2000, 10, 2016, nullptr},
        {Wd1, 10, 2000, 32, nullptr},    {Wd2, 2000, 500, 2016, nullptr},
        {Wd3, 500, 500, 512, nullptr},   {Wxb, 500, 1000, 512, nullptr},
        {feaW[0], 1000, 500, 1024, nullptr}, {feaW[1], 500, 500, 512, nullptr},
        {feaW[2], 500, 2000, 512, nullptr},  {feaW[3], 2000, 10, 2016, nullptr},
        {topoW[0], 1000, 500, 1024, nullptr}, {topoW[1], 500, 500, 512, nullptr},
        {topoW[2], 500, 2000, 512, nullptr},  {topoW[3], 2000, 10, 2016, nullptr},
    };
    for (int i = 0; i < 16; ++i) {
        tw[i].Kp = kpad(tw[i].K);
        tw[i].Bt = (ushort*)alloc((size_t)tw[i].Nc * tw[i].Kp * 2);
        int tot = tw[i].Nc * tw[i].Kp;
        transpose_w<<<(tot + 255) / 256, 256, 0, stream>>>(
            tw[i].W, tw[i].Bt, tw[i].K, tw[i].Nc, tw[i].Kp);
    }

    auto gemm_f = [&](const float* A, const TW& t, const float* bias, float* C,
                      int act, int split) {
        dim3 g((t.Nc + 127) / 128, (N_NODES + 127) / 128);
        mfma_gemm<<<g, 256, 0, stream>>>(A, t.Bt, bias, C, nullptr, N_NODES, t.K,
                                         t.Nc, t.Kp, act, split);
    };
    auto gemm_b = [&](const float* A, const TW& t, ushort* C) {
        dim3 g((t.Nc + 127) / 128, (N_NODES + 127) / 128);
        mfma_gemm<<<g, 256, 0, stream>>>(A, t.Bt, nullptr, nullptr, C, N_NODES, t.K,
                                         t.Nc, t.Kp, 0, 0);
    };

    // ---------------- AE branch ----------------
    gemm_f(x, tw[0], be1, feah1, 1, 0);       // h1
    gemm_f(feah1, tw[1], be2, feah2, 1, 0);   // h2
    gemm_f(feah2, tw[2], be3, bufF, 1, 0);    // h3
    gemm_f(bufF, tw[3], bz1, z1buf, 0, 0);    // z1
    gemm_small<<<(N_NODES + 7) / 8, 256, 0, stream>>>(z1buf, Wz2, bz2, out_z,
                                                      N_NODES, 10, 10, 0);  // z
    gemm_small<<<(N_NODES + 7) / 8, 256, 0, stream>>>(out_z, Wd0, bd0, dsmall,
                                                      N_NODES, 10, 10, 1);  // d0
    gemm_f(dsmall, tw[4], bd1, bufF, 1, 0);   // d1
    gemm_f(bufF, tw[5], bd2, feah1, 1, 0);    // d2 (feah1 scratch)
    gemm_f(feah1, tw[6], bd3, feah2, 1, 0);   // d3 (feah2 scratch)
    gemm_f(feah2, tw[7], bxb, out_xbar, 0, 0);  // x_bar

    // ---------------- GNN branches ----------------
    struct Br {
        const int* rows; const int* cols; const float* vals;
        int w0;          // index into tw[] of this branch's W1
        int precise;     // 1 = fp32 sup/t + split-A GEMM (fea branch)
        float* dest[4];
    };
    // fea branch FIRST: it uses bufH for fp32 sup; branches 1-3 then reuse bufH as h.
    Br brs[4] = {
        {fadj_rows, fadj_cols, fadj_vals, 8, 1, {feah1, feah2, feah3, out_fea4}},
        {adj_rows, adj_cols, adj_vals, 12, 0, {bufH, bufH, bufH, out_topo4}},
        {f2_rows, f2_cols, f2_vals, 8, 0, {bufH, bufH, bufH, out_feadiff4}},
        {f1_rows, f1_cols, f1_vals, 12, 0, {bufH, bufH, bufH, out_topodiff4}},
    };
    const int outD[4] = {500, 500, 2000, 10};

    for (int b = 0; b < 4; ++b) {
        zero_i32<<<(N_NODES + 255) / 256, 256, 0, stream>>>(counts, N_NODES);
        hist_kernel<<<(N_EDGES + 255) / 256, 256, 0, stream>>>(brs[b].rows, counts);
        scan_kernel<<<1, 1024, 0, stream>>>(counts, row_ptr);
        zero_i32<<<(N_NODES + 255) / 256, 256, 0, stream>>>(fillctr, N_NODES);
        fill_kernel<<<(N_EDGES + 255) / 256, 256, 0, stream>>>(
            brs[b].rows, brs[b].cols, brs[b].vals, row_ptr, fillctr, cols_s, vals_s);

        const float* h = x;
        for (int L = 0; L < 4; ++L) {
            int C = outD[L];
            float* dest = brs[b].dest[L];
            zero_i32<<<(C + 255) / 256, 256, 0, stream>>>((int*)ssum, C);
            zero_i32<<<(C + 255) / 256, 256, 0, stream>>>((int*)ssq, C);
            if (brs[b].precise) {
                // fp32 path: sup -> bufH, t -> dest, BN in-place on dest
                gemm_f(h, tw[brs[b].w0 + L], nullptr, bufH, 0, 1);  // split-A
                spmm_act_f<<<dim3(N_NODES, (C + 255) / 256), 256, 0, stream>>>(
                    bufH, row_ptr, cols_s, vals_s, dest, C);
                col_stats_f<<<dim3((C + 255) / 256, 40), 256, 0, stream>>>(
                    dest, ssum, ssq, C);
                bn_apply_f<<<dim3((C + 255) / 256, N_NODES), 256, 0, stream>>>(
                    dest, ssum, ssq, dest, C);
            } else {
                gemm_b(h, tw[brs[b].w0 + L], bufB);  // sup (bf16)
                spmm_act_bf<<<dim3(N_NODES, (C + 511) / 512), 256, 0, stream>>>(
                    bufB, row_ptr, cols_s, vals_s, bufC, C);
                col_stats<<<dim3((C + 255) / 256, 40), 256, 0, stream>>>(
                    bufC, ssum, ssq, C);
                bn_apply<<<dim3((C + 255) / 256, N_NODES), 256, 0, stream>>>(
                    bufC, ssum, ssq, dest, C);
            }
            h = dest;
        }
    }

    // ---------------- attention fusion head ----------------
    mlp_u<<<(N_NODES + 3) / 4, 256, 0, stream>>>(feah1, feah2, feah3, out_fea4,
                                                 mlpW, mlpb, ubuf);
    zout_kernel<<<dim3(12, N_NODES), 256, 0, stream>>>(feah1, feah2, feah3, out_fea4,
                                                       ubuf, out_zout);
}